// Round 11
// baseline (227.861 us; speedup 1.0000x reference)
//
#include <hip/hip_runtime.h>

// ActivationSparsifier: per row of D=4096, t = 409-th largest |x|,
// out = x * sigmoid(10 * (|x| - t)).
//
// R11 = R9 (best measured: dur_us 226.48) + first-generation STAGGER,
// reimplemented without the R10 sleep-loop (R10 failed the container;
// unclear if infra or source — this variant uses single flat s_sleep
// calls with compile-time immediates <= 127, the ISA's 7-bit cap).
//
// Theory under test (last unfalsified axis after 10 structural probes
// all pinned at 76-84 us with HBM ~31% / VALU ~21% / all pipes idle):
// co-resident blocks per CU start together and run identical barrier
// cadences -> load phases coincide -> memory duty cycle ~55%. Stagger
// generation g (co-residents differ in blockIdx>>8) by g*1024 cycles
// (s_sleep 16g: 16*64 = 1024 cyc/step, spread 0..7k vs ~30k block
// wall). Steady state self-sustains via staggered completions.
// Null-case cost <= ~7k cycles one-time on gen 1..7 blocks (~+1 us).
//
// Everything below the stagger is byte-identical to R9: 256-thread
// block per row, row in registers, unpacked hist[4096], plain
// __syncthreads, normal cached stores, rcp epilogue.
//
// Threshold numerics unchanged: 2-pass radix select (12-bit digit bits
// 30:19, then 8-bit bits 18:11), 20-bit prefix threshold, rel err <=
// 2^-11 -> output delta ~2e-3, far under harness floor (~0.0156).

constexpr int D = 4096;
constexpr int K = 409;          // max(1, int(D * 0.1))
constexpr int NT = 256;
constexpr int NB0 = 4096;       // pass-0 bins
constexpr int SH0 = 19;         // pass-0 digit shift (12 bits: 30:19)
constexpr int SH1 = 11;         // pass-1 digit shift (8 bits: 18:11)
constexpr float SHARP = 10.0f;

__device__ __forceinline__ float softmask(float xv, float t) {
  // x * sigmoid(SHARP*(|x|-t)) = x * rcp(1 + exp(SHARP*(t-|x|)))
  return xv * __builtin_amdgcn_rcpf(1.0f + __expf(SHARP * (t - fabsf(xv))));
}

__global__ __launch_bounds__(NT, 8) void ActSp_row(
    const float* __restrict__ x, float* __restrict__ y) {
  const size_t row = blockIdx.x;

  // ---- first-generation stagger: desynchronize co-resident blocks ----
  // s_sleep immediate is 7-bit (sleep = 64*imm cycles). One flat switch,
  // no loops: generation g sleeps g*1024 cycles before issuing loads.
  if (blockIdx.x < 2048u) {
    switch ((blockIdx.x >> 8) & 7u) {
      case 1u: __builtin_amdgcn_s_sleep(16); break;   // 1024 cyc
      case 2u: __builtin_amdgcn_s_sleep(32); break;   // 2048
      case 3u: __builtin_amdgcn_s_sleep(48); break;   // 3072
      case 4u: __builtin_amdgcn_s_sleep(64); break;   // 4096
      case 5u: __builtin_amdgcn_s_sleep(80); break;   // 5120
      case 6u: __builtin_amdgcn_s_sleep(96); break;   // 6144
      case 7u: __builtin_amdgcn_s_sleep(112); break;  // 7168
      default: break;
    }
  }

  const float4* __restrict__ x4 = reinterpret_cast<const float4*>(x + row * D);
  float4* __restrict__ y4 = reinterpret_cast<float4*>(y + row * (size_t)D);
  const int tid = threadIdx.x;
  const int lane = tid & 63;
  const int wave = tid >> 6;

  // ---- load row: 16 floats/thread, coalesced float4 ----
  float4 v[4];
#pragma unroll
  for (int i = 0; i < 4; ++i) v[i] = x4[tid + i * NT];

  __shared__ unsigned hist[NB0];
  __shared__ unsigned hist1[NT];
  __shared__ unsigned wt[4];
  __shared__ unsigned bc[2];  // bc[0]=digit/prefix, bc[1]=residual k

  // zero pass-0 histogram (b128 stores); overlaps in-flight global loads
  uint4* h4 = reinterpret_cast<uint4*>(hist);
#pragma unroll
  for (int i = 0; i < 4; ++i) h4[tid + i * NT] = make_uint4(0u, 0u, 0u, 0u);
  __syncthreads();  // B1

  // ---- pass 0: 12-bit histogram (abs bits on the fly) ----
#pragma unroll
  for (int i = 0; i < 4; ++i) {
    atomicAdd(&hist[(__float_as_uint(v[i].x) & 0x7fffffffu) >> SH0], 1u);
    atomicAdd(&hist[(__float_as_uint(v[i].y) & 0x7fffffffu) >> SH0], 1u);
    atomicAdd(&hist[(__float_as_uint(v[i].z) & 0x7fffffffu) >> SH0], 1u);
    atomicAdd(&hist[(__float_as_uint(v[i].w) & 0x7fffffffu) >> SH0], 1u);
  }
  __syncthreads();  // B2

  // ---- pass 0 scan: thread owns bins [tid*16, tid*16+16) ----
  unsigned T = 0;
  {
    const uint4* hb = reinterpret_cast<const uint4*>(&hist[tid * 16]);
#pragma unroll
    for (int w2 = 0; w2 < 4; ++w2) {
      uint4 a = hb[w2];
      T += a.x + a.y + a.z + a.w;
    }
  }
  unsigned suf = T;  // wave-level inclusive suffix scan (lanes >= lane)
#pragma unroll
  for (int off = 1; off < 64; off <<= 1) {
    unsigned nb = __shfl_down(suf, off, 64);
    if (lane + off < 64) suf += nb;
  }
  if (lane == 0) wt[wave] = suf;
  __syncthreads();  // B3

  unsigned above = suf - T;
#pragma unroll
  for (int w = 0; w < 4; ++w)
    if (w > wave) above += wt[w];

  hist1[tid] = 0;  // zero pass-1 bins (separate array - no read hazard)

  if (above < (unsigned)K && above + T >= (unsigned)K) {
    // crossing thread: re-read my 16 bins high-to-low, one uint4 at a
    // time; pick largest bin with cumulative(count of bins >= it) >= K
    const uint4* hb = reinterpret_cast<const uint4*>(&hist[tid * 16]);
    unsigned run = above;
    unsigned snext = above;
    int jstar = 0;
    bool done = false;
#pragma unroll
    for (int w2 = 3; w2 >= 0; --w2) {
      uint4 a = hb[w2];
      unsigned c4[4] = {a.x, a.y, a.z, a.w};
#pragma unroll
      for (int j = 3; j >= 0; --j) {
        if (!done) {
          if (run + c4[j] >= (unsigned)K) { jstar = w2 * 4 + j; snext = run; done = true; }
          else run += c4[j];
        }
      }
    }
    bc[0] = (unsigned)(tid * 16 + jstar);  // 12-bit digit d0
    bc[1] = (unsigned)K - snext;           // residual k for pass 1
  }
  __syncthreads();  // B4

  const unsigned d0 = bc[0];
  const unsigned k1 = bc[1];

  // ---- pass 1: 8-bit histogram over candidates matching d0 ----
#pragma unroll
  for (int i = 0; i < 4; ++i) {
    unsigned a0 = __float_as_uint(v[i].x) & 0x7fffffffu;
    unsigned a1 = __float_as_uint(v[i].y) & 0x7fffffffu;
    unsigned a2 = __float_as_uint(v[i].z) & 0x7fffffffu;
    unsigned a3 = __float_as_uint(v[i].w) & 0x7fffffffu;
    if ((a0 >> SH0) == d0) atomicAdd(&hist1[(a0 >> SH1) & 255u], 1u);
    if ((a1 >> SH0) == d0) atomicAdd(&hist1[(a1 >> SH1) & 255u], 1u);
    if ((a2 >> SH0) == d0) atomicAdd(&hist1[(a2 >> SH1) & 255u], 1u);
    if ((a3 >> SH0) == d0) atomicAdd(&hist1[(a3 >> SH1) & 255u], 1u);
  }
  __syncthreads();  // B5

  // ---- pass 1 scan: one bin per thread ----
  unsigned T1 = hist1[tid];
  unsigned suf1 = T1;
#pragma unroll
  for (int off = 1; off < 64; off <<= 1) {
    unsigned nb = __shfl_down(suf1, off, 64);
    if (lane + off < 64) suf1 += nb;
  }
  if (lane == 0) wt[wave] = suf1;
  __syncthreads();  // B6

  unsigned above1 = suf1 - T1;
#pragma unroll
  for (int w = 0; w < 4; ++w)
    if (w > wave) above1 += wt[w];

  if (above1 < k1 && above1 + T1 >= k1) {
    bc[0] = (d0 << SH0) | ((unsigned)tid << SH1);
  }
  __syncthreads();  // B7

  // ---- apply soft mask and store (normal cached stores, per R9) ----
  const float t = __uint_as_float(bc[0]);
#pragma unroll
  for (int i = 0; i < 4; ++i) {
    float4 o;
    o.x = softmask(v[i].x, t);
    o.y = softmask(v[i].y, t);
    o.z = softmask(v[i].z, t);
    o.w = softmask(v[i].w, t);
    y4[tid + i * NT] = o;
  }
}

extern "C" void kernel_launch(void* const* d_in, const int* in_sizes, int n_in,
                              void* d_out, int out_size, void* d_ws, size_t ws_size,
                              hipStream_t stream) {
  (void)n_in; (void)d_ws; (void)ws_size; (void)out_size;
  const float* x = (const float*)d_in[0];
  float* y = (float*)d_out;
  const int rows = in_sizes[0] / D;  // 8192
  ActSp_row<<<dim3(rows), dim3(NT), 0, stream>>>(x, y);
}